// Round 1
// baseline (404.639 us; speedup 1.0000x reference)
//
#include <hip/hip_runtime.h>

#define V 8192
#define RPB 4  // rows of M per block in the kinetic kernel

// ws layout (floats): [0]=kinetic raw sum, [1]=elastic sum, [16..16+3V)=delta SoA
__global__ __launch_bounds__(256) void prep_kernel(
    const float* __restrict__ next_pos, const float* __restrict__ pos,
    const float* __restrict__ vel, const float* __restrict__ ext,
    const float* __restrict__ dt_p, float* __restrict__ ws) {
  int i = blockIdx.x * blockDim.x + threadIdx.x;
  if (i < 2) ws[i] = 0.f;  // zero accumulators every call (ws is poisoned)
  if (i < V) {
    float dt = dt_p[0];
    float dt2 = dt * dt;
    float* dx = ws + 16;
    float* dy = dx + V;
    float* dz = dy + V;
    dx[i] = next_pos[3*i+0] - (pos[3*i+0] + vel[3*i+0]*dt + ext[3*i+0]*dt2);
    dy[i] = next_pos[3*i+1] - (pos[3*i+1] + vel[3*i+1]*dt + ext[3*i+1]*dt2);
    dz[i] = next_pos[3*i+2] - (pos[3*i+2] + vel[3*i+2]*dt + ext[3*i+2]*dt2);
  }
}

// kinetic raw sum: sum_i delta[i] . (M delta)[i], accumulated into ws[0]
__global__ __launch_bounds__(256) void kinetic_kernel(
    const float* __restrict__ M, const float* __restrict__ dsoa,
    float* __restrict__ acc) {
  const float* __restrict__ dx = dsoa;
  const float* __restrict__ dy = dsoa + V;
  const float* __restrict__ dz = dsoa + 2 * V;
  const int r0 = blockIdx.x * RPB;
  const int t = threadIdx.x;

  float s[RPB][3];
#pragma unroll
  for (int r = 0; r < RPB; ++r) s[r][0] = s[r][1] = s[r][2] = 0.f;

#pragma unroll
  for (int it = 0; it < 8; ++it) {
    const int j = 4 * t + 1024 * it;
    const float4 x4 = *(const float4*)(dx + j);
    const float4 y4 = *(const float4*)(dy + j);
    const float4 z4 = *(const float4*)(dz + j);
#pragma unroll
    for (int r = 0; r < RPB; ++r) {
      const float4 m4 = *(const float4*)(M + (size_t)(r0 + r) * V + j);
      s[r][0] += m4.x * x4.x + m4.y * x4.y + m4.z * x4.z + m4.w * x4.w;
      s[r][1] += m4.x * y4.x + m4.y * y4.y + m4.z * y4.z + m4.w * y4.w;
      s[r][2] += m4.x * z4.x + m4.y * z4.y + m4.z * z4.z + m4.w * z4.w;
    }
  }

  // 64-lane wave reduction of the 12 partials
#pragma unroll
  for (int r = 0; r < RPB; ++r)
#pragma unroll
    for (int k = 0; k < 3; ++k) {
      float v = s[r][k];
#pragma unroll
      for (int off = 32; off; off >>= 1) v += __shfl_down(v, off, 64);
      s[r][k] = v;
    }

  __shared__ float lds[4][RPB * 3];
  const int lane = t & 63, wv = t >> 6;
  if (lane == 0) {
#pragma unroll
    for (int r = 0; r < RPB; ++r)
#pragma unroll
      for (int k = 0; k < 3; ++k) lds[wv][r * 3 + k] = s[r][k];
  }
  __syncthreads();
  if (t == 0) {
    float c = 0.f;
#pragma unroll
    for (int r = 0; r < RPB; ++r) {
      float S0 = lds[0][r*3+0] + lds[1][r*3+0] + lds[2][r*3+0] + lds[3][r*3+0];
      float S1 = lds[0][r*3+1] + lds[1][r*3+1] + lds[2][r*3+1] + lds[3][r*3+1];
      float S2 = lds[0][r*3+2] + lds[1][r*3+2] + lds[2][r*3+2] + lds[3][r*3+2];
      c += dx[r0 + r] * S0 + dy[r0 + r] * S1 + dz[r0 + r] * S2;
    }
    atomicAdd(acc, c);
  }
}

__global__ __launch_bounds__(256) void elastic_kernel(
    const float* __restrict__ next_pos, const int* __restrict__ elements,
    const float* __restrict__ poly, const float* __restrict__ measure,
    const float* __restrict__ lam, const float* __restrict__ mu,
    float* __restrict__ acc, int E) {
  int e = blockIdx.x * blockDim.x + threadIdx.x;
  float contrib = 0.f;
  if (e < E) {
    float F00 = 0.f, F01 = 0.f, F02 = 0.f;
    float F10 = 0.f, F11 = 0.f, F12 = 0.f;
    float F20 = 0.f, F21 = 0.f, F22 = 0.f;
#pragma unroll
    for (int f = 0; f < 4; ++f) {
      int vi = elements[e * 4 + f];
      const float* p = next_pos + 3 * (size_t)vi;
      float px = p[0], py = p[1], pz = p[2];
      const float* b = poly + (size_t)e * 16 + f * 4;
      float b0 = b[0], b1 = b[1], b2 = b[2];
      F00 += px * b0; F01 += px * b1; F02 += px * b2;
      F10 += py * b0; F11 += py * b1; F12 += py * b2;
      F20 += pz * b0; F21 += pz * b1; F22 += pz * b2;
    }
    float Ic = F00*F00 + F01*F01 + F02*F02 +
               F10*F10 + F11*F11 + F12*F12 +
               F20*F20 + F21*F21 + F22*F22;
    float J = F00 * (F11 * F22 - F12 * F21)
            - F01 * (F10 * F22 - F12 * F20)
            + F02 * (F10 * F21 - F11 * F20);
    float l = lam[e], m = mu[e];
    float alpha = 0.75f * m / l + 1.f;  // (1 - 1/(3+1))*mu/lam + 1
    float Icv = fmaxf(Ic + 1.f, 0.f);
    float d = J - alpha;
    float psi = 0.5f * m * (Ic - 3.f) + 0.5f * l * d * d
              - 0.5f * m * logf(Icv + 1e-30f);
    contrib = psi * measure[e * 4 + 3];
  }
#pragma unroll
  for (int off = 32; off; off >>= 1) contrib += __shfl_down(contrib, off, 64);
  __shared__ float w[4];
  int lane = threadIdx.x & 63, wv = threadIdx.x >> 6;
  if (lane == 0) w[wv] = contrib;
  __syncthreads();
  if (threadIdx.x == 0) atomicAdd(acc, w[0] + w[1] + w[2] + w[3]);
}

__global__ void finalize_kernel(const float* __restrict__ ws,
                                const float* __restrict__ dt_p,
                                float* __restrict__ out) {
  float dt = dt_p[0];
  float inv_h = 1.f / dt;
  float coeff = 0.5f * inv_h * inv_h;
  float kin = coeff * ws[0];
  float ela = ws[1];
  out[0] = kin + ela;
  out[1] = kin;
  out[2] = ela;
}

extern "C" void kernel_launch(void* const* d_in, const int* in_sizes, int n_in,
                              void* d_out, int out_size, void* d_ws, size_t ws_size,
                              hipStream_t stream) {
  const float* next_pos = (const float*)d_in[0];
  const float* pos      = (const float*)d_in[1];
  const float* vel      = (const float*)d_in[2];
  const float* ext      = (const float*)d_in[3];
  const float* M        = (const float*)d_in[4];
  const int*   elements = (const int*)d_in[5];
  const float* poly     = (const float*)d_in[6];
  const float* measure  = (const float*)d_in[7];
  const float* lam      = (const float*)d_in[8];
  const float* mu       = (const float*)d_in[9];
  const float* dt_p     = (const float*)d_in[10];
  float* out = (float*)d_out;
  float* ws  = (float*)d_ws;
  const int E = in_sizes[5] / 4;

  prep_kernel<<<(V + 255) / 256, 256, 0, stream>>>(next_pos, pos, vel, ext, dt_p, ws);
  kinetic_kernel<<<V / RPB, 256, 0, stream>>>(M, ws + 16, ws);
  elastic_kernel<<<(E + 255) / 256, 256, 0, stream>>>(next_pos, elements, poly,
                                                      measure, lam, mu, ws + 1, E);
  finalize_kernel<<<1, 1, 0, stream>>>(ws, dt_p, out);
}

// Round 2
// 388.543 us; speedup vs baseline: 1.0414x; 1.0414x over previous
//
#include <hip/hip_runtime.h>

#define V 8192
#define RPW 2          // rows of M per wave in the kinetic kernel
#define KBLOCKS (V / (RPW * 4))  // 1024 blocks, 4 waves each -> V/RPW waves

// ws layout (floats): [0]=kinetic raw sum, [1]=elastic sum, [16..16+3V)=delta SoA
__global__ __launch_bounds__(256) void prep_kernel(
    const float* __restrict__ next_pos, const float* __restrict__ pos,
    const float* __restrict__ vel, const float* __restrict__ ext,
    const float* __restrict__ dt_p, float* __restrict__ ws) {
  int i = blockIdx.x * blockDim.x + threadIdx.x;
  if (i < 2) ws[i] = 0.f;  // zero accumulators every call (ws is poisoned)
  if (i < V) {
    float dt = dt_p[0];
    float dt2 = dt * dt;
    float* dx = ws + 16;
    float* dy = dx + V;
    float* dz = dy + V;
    dx[i] = next_pos[3*i+0] - (pos[3*i+0] + vel[3*i+0]*dt + ext[3*i+0]*dt2);
    dy[i] = next_pos[3*i+1] - (pos[3*i+1] + vel[3*i+1]*dt + ext[3*i+1]*dt2);
    dz[i] = next_pos[3*i+2] - (pos[3*i+2] + vel[3*i+2]*dt + ext[3*i+2]*dt2);
  }
}

// kinetic raw sum: sum_{r,c} M[r,c] * (dx[r]dx[c] + dy[r]dy[c] + dz[r]dz[c])
// One wave owns RPW rows; lanes stride float4 across columns. Single scalar
// accumulator per thread -> ~60 VGPRs, loads stay pipelined.
__global__ __launch_bounds__(256) void kinetic_kernel(
    const float* __restrict__ M, const float* __restrict__ dsoa,
    float* __restrict__ acc) {
  const float* __restrict__ dx = dsoa;
  const float* __restrict__ dy = dsoa + V;
  const float* __restrict__ dz = dsoa + 2 * V;
  const float4* __restrict__ dx4 = (const float4*)dx;
  const float4* __restrict__ dy4 = (const float4*)dy;
  const float4* __restrict__ dz4 = (const float4*)dz;

  const int t = threadIdx.x;
  const int lane = t & 63;
  const int wv = t >> 6;
  const int wave = blockIdx.x * 4 + wv;   // global wave id
  const int r0 = wave * RPW;

  // row-uniform delta components (hardware-broadcast same-address loads)
  float rx[RPW], ry[RPW], rz[RPW];
#pragma unroll
  for (int r = 0; r < RPW; ++r) {
    rx[r] = dx[r0 + r];
    ry[r] = dy[r0 + r];
    rz[r] = dz[r0 + r];
  }

  float a = 0.f;
#pragma unroll 2
  for (int i = 0; i < V / 4 / 64; ++i) {   // 32 iterations
    const int k = i * 64 + lane;           // float4 chunk index in the row
    const float4 cx = dx4[k];
    const float4 cy = dy4[k];
    const float4 cz = dz4[k];
#pragma unroll
    for (int r = 0; r < RPW; ++r) {
      const float4 m = *(const float4*)(M + (size_t)(r0 + r) * V + 4 * k);
      a += m.x * (rx[r]*cx.x + ry[r]*cy.x + rz[r]*cz.x);
      a += m.y * (rx[r]*cx.y + ry[r]*cy.y + rz[r]*cz.y);
      a += m.z * (rx[r]*cx.z + ry[r]*cy.z + rz[r]*cz.z);
      a += m.w * (rx[r]*cx.w + ry[r]*cy.w + rz[r]*cz.w);
    }
  }

  // 64-lane wave reduction
#pragma unroll
  for (int off = 32; off; off >>= 1) a += __shfl_down(a, off, 64);

  __shared__ float lds[4];
  if (lane == 0) lds[wv] = a;
  __syncthreads();
  if (t == 0) atomicAdd(acc, lds[0] + lds[1] + lds[2] + lds[3]);
}

__global__ __launch_bounds__(256) void elastic_kernel(
    const float* __restrict__ next_pos, const int* __restrict__ elements,
    const float* __restrict__ poly, const float* __restrict__ measure,
    const float* __restrict__ lam, const float* __restrict__ mu,
    float* __restrict__ acc, int E) {
  int e = blockIdx.x * blockDim.x + threadIdx.x;
  float contrib = 0.f;
  if (e < E) {
    float F00 = 0.f, F01 = 0.f, F02 = 0.f;
    float F10 = 0.f, F11 = 0.f, F12 = 0.f;
    float F20 = 0.f, F21 = 0.f, F22 = 0.f;
#pragma unroll
    for (int f = 0; f < 4; ++f) {
      int vi = elements[e * 4 + f];
      const float* p = next_pos + 3 * (size_t)vi;
      float px = p[0], py = p[1], pz = p[2];
      const float* b = poly + (size_t)e * 16 + f * 4;
      float b0 = b[0], b1 = b[1], b2 = b[2];
      F00 += px * b0; F01 += px * b1; F02 += px * b2;
      F10 += py * b0; F11 += py * b1; F12 += py * b2;
      F20 += pz * b0; F21 += pz * b1; F22 += pz * b2;
    }
    float Ic = F00*F00 + F01*F01 + F02*F02 +
               F10*F10 + F11*F11 + F12*F12 +
               F20*F20 + F21*F21 + F22*F22;
    float J = F00 * (F11 * F22 - F12 * F21)
            - F01 * (F10 * F22 - F12 * F20)
            + F02 * (F10 * F21 - F11 * F20);
    float l = lam[e], m = mu[e];
    float alpha = 0.75f * m / l + 1.f;  // (1 - 1/(3+1))*mu/lam + 1
    float Icv = fmaxf(Ic + 1.f, 0.f);
    float d = J - alpha;
    float psi = 0.5f * m * (Ic - 3.f) + 0.5f * l * d * d
              - 0.5f * m * logf(Icv + 1e-30f);
    contrib = psi * measure[e * 4 + 3];
  }
#pragma unroll
  for (int off = 32; off; off >>= 1) contrib += __shfl_down(contrib, off, 64);
  __shared__ float w[4];
  int lane = threadIdx.x & 63, wv = threadIdx.x >> 6;
  if (lane == 0) w[wv] = contrib;
  __syncthreads();
  if (threadIdx.x == 0) atomicAdd(acc, w[0] + w[1] + w[2] + w[3]);
}

__global__ void finalize_kernel(const float* __restrict__ ws,
                                const float* __restrict__ dt_p,
                                float* __restrict__ out) {
  float dt = dt_p[0];
  float inv_h = 1.f / dt;
  float coeff = 0.5f * inv_h * inv_h;
  float kin = coeff * ws[0];
  float ela = ws[1];
  out[0] = kin + ela;
  out[1] = kin;
  out[2] = ela;
}

extern "C" void kernel_launch(void* const* d_in, const int* in_sizes, int n_in,
                              void* d_out, int out_size, void* d_ws, size_t ws_size,
                              hipStream_t stream) {
  const float* next_pos = (const float*)d_in[0];
  const float* pos      = (const float*)d_in[1];
  const float* vel      = (const float*)d_in[2];
  const float* ext      = (const float*)d_in[3];
  const float* M        = (const float*)d_in[4];
  const int*   elements = (const int*)d_in[5];
  const float* poly     = (const float*)d_in[6];
  const float* measure  = (const float*)d_in[7];
  const float* lam      = (const float*)d_in[8];
  const float* mu       = (const float*)d_in[9];
  const float* dt_p     = (const float*)d_in[10];
  float* out = (float*)d_out;
  float* ws  = (float*)d_ws;
  const int E = in_sizes[5] / 4;

  prep_kernel<<<(V + 255) / 256, 256, 0, stream>>>(next_pos, pos, vel, ext, dt_p, ws);
  kinetic_kernel<<<KBLOCKS, 256, 0, stream>>>(M, ws + 16, ws);
  elastic_kernel<<<(E + 255) / 256, 256, 0, stream>>>(next_pos, elements, poly,
                                                      measure, lam, mu, ws + 1, E);
  finalize_kernel<<<1, 1, 0, stream>>>(ws, dt_p, out);
}